// Round 10
// baseline (390.458 us; speedup 1.0000x reference)
//
#include <hip/hip_runtime.h>

// d_out is FLOAT32 (reference outputs are int32/float32 -> "else float*").
// out_size = 43,584,000 f32: order[8,100000] | sh[8,100000] |
// nei[8,40,40,40,27,3] | mask[8,40,40,40]. Ref is bf16-quantized; threshold
// 7659.52 = 2% of 382976. Writing exact integer-valued floats -> err <= 862.

#define VB    8
#define VN    100000
#define VKEYS 64000        // 40^3 compact keys (lex == hash order)
#define VBLK  250          // VKEYS/256
#define VGX   391          // ceil(VN/256)

// f32 element offsets
#define O_ORDER 0
#define O_SH    800000
#define O_NEI   1600000
#define O_MASK  43072000
#define NEI_PER_B 5184000  // 64000*27*3 (identical values for every batch)
#define NEI_T   1296000    // NEI_PER_B/4 threads, one float4 each, 8 batch stores

// u32 scratch carved inside the nei f32 region (slots 40,000,000..41,314,008;
// nei spans [1,600,000, 43,072,000) and is fully rewritten LAST by vox_neigh).
// d_ws is never used. Layout: seg[8*64000] | mx[8] | bs[8*250] | ord[8*100000]
#define CARVE_F32_OFF 40000000

__device__ __forceinline__ unsigned vox_key(const float* __restrict__ p) {
    int cx = (int)(p[0] * 39.0f);
    int cy = (int)(p[1] * 39.0f);
    int cz = (int)(p[2] * 39.0f);
    cx = cx < 0 ? 0 : (cx > 39 ? 39 : cx);
    cy = cy < 0 ? 0 : (cy > 39 ? 39 : cy);
    cz = cz < 0 ? 0 : (cz > 39 ? 39 : cz);
    return (unsigned)(cx * 1600 + cy * 40 + cz);
}

__global__ void vox_zero(unsigned* __restrict__ p, int n) {
    int i = blockIdx.x * 256 + threadIdx.x;
    if (i < n) p[i] = 0u;
}

// histogram + per-batch max occupied key
__global__ void vox_hist(const float* __restrict__ pc, unsigned* __restrict__ seg,
                         unsigned* __restrict__ mx) {
    int n = blockIdx.x * 256 + threadIdx.x;
    int b = blockIdx.y;
    unsigned key = 0;
    if (n < VN) {
        key = vox_key(pc + ((size_t)b * VN + n) * 3);
        atomicAdd(&seg[b * VKEYS + key], 1u);
    }
    unsigned km = key;
    #pragma unroll
    for (int o = 32; o; o >>= 1) {
        unsigned t = (unsigned)__shfl_xor((int)km, o, 64);
        km = km > t ? km : t;
    }
    if ((threadIdx.x & 63) == 0) atomicMax(&mx[b], km);
}

__global__ void vox_scanA(unsigned* __restrict__ seg, unsigned* __restrict__ bs) {
    int b = blockIdx.y;
    int bin = blockIdx.x * 256 + threadIdx.x;
    __shared__ unsigned s[256];
    unsigned v = seg[b * VKEYS + bin];
    s[threadIdx.x] = v;
    __syncthreads();
    #pragma unroll
    for (int o = 1; o < 256; o <<= 1) {
        unsigned t = (threadIdx.x >= o) ? s[threadIdx.x - o] : 0u;
        __syncthreads();
        s[threadIdx.x] += t;
        __syncthreads();
    }
    seg[b * VKEYS + bin] = s[threadIdx.x] - v;   // exclusive within block
    if (threadIdx.x == 255) bs[b * VBLK + blockIdx.x] = s[255];
}

__global__ void vox_scanB(unsigned* __restrict__ bs) {
    int b = blockIdx.x;
    int t = threadIdx.x;
    __shared__ unsigned s[256];
    unsigned v = (t < VBLK) ? bs[b * VBLK + t] : 0u;
    s[t] = v;
    __syncthreads();
    #pragma unroll
    for (int o = 1; o < 256; o <<= 1) {
        unsigned tv = (t >= o) ? s[t - o] : 0u;
        __syncthreads();
        s[t] += tv;
        __syncthreads();
    }
    if (t < VBLK) bs[b * VBLK + t] = s[t] - v;
}

__global__ void vox_scanC(unsigned* __restrict__ seg, const unsigned* __restrict__ bs) {
    int b = blockIdx.y;
    int bin = blockIdx.x * 256 + threadIdx.x;
    seg[b * VKEYS + bin] += bs[b * VBLK + blockIdx.x];
}

__global__ void vox_scatter(const float* __restrict__ pc, unsigned* __restrict__ seg,
                            unsigned* __restrict__ ord) {
    int n = blockIdx.x * 256 + threadIdx.x;
    int b = blockIdx.y;
    if (n >= VN) return;
    unsigned key = vox_key(pc + ((size_t)b * VN + n) * 3);
    unsigned pos = atomicAdd(&seg[b * VKEYS + key], 1u);
    if (pos < VN) ord[(size_t)b * VN + pos] = (unsigned)n;
}

// per-bucket stable fix-up + emit order/sh/mask as f32
// post-scatter: seg[bin] = segment end; seg[bin-1] = segment start
__global__ void vox_emit(const unsigned* __restrict__ seg, const unsigned* __restrict__ mx,
                         unsigned* __restrict__ ord, float* __restrict__ out) {
    int bin = blockIdx.x * 256 + threadIdx.x;   // == linear voxel index
    int b = blockIdx.y;
    unsigned end = seg[b * VKEYS + bin];
    unsigned st  = bin ? seg[b * VKEYS + bin - 1] : 0u;
    // mask: occupied -> 1, except max-hash voxel (boundary sh[:-1]!=sh[1:]
    // excludes the final group's last element); key order == hash order (lex)
    out[(size_t)O_MASK + (size_t)b * VKEYS + bin] =
        (end > st && (unsigned)bin != mx[b]) ? 1.0f : 0.0f;
    if (end <= st || end > VN || st > VN) return;
    unsigned* o = ord + (size_t)b * VN;
    // stable tie-break: ascending point index (jnp.argsort is stable)
    for (unsigned a = st; a + 1 < end; a++) {
        unsigned mi = a, mv = o[a];
        for (unsigned c = a + 1; c < end; c++) {
            unsigned cv = o[c];
            if (cv < mv) { mv = cv; mi = c; }
        }
        if (mi != a) { unsigned tt = o[a]; o[a] = mv; o[mi] = tt; }
    }
    int x = bin / 1600, y = (bin / 40) % 40, z = bin % 40;
    float hb = (float)(x * 10000 + y * 100 + z);
    for (unsigned q = st; q < end; q++) {
        out[(size_t)O_ORDER + (size_t)b * VN + q] = (float)o[q];
        out[(size_t)O_SH + (size_t)b * VN + q] = hb;
    }
}

// neighbour list: values identical across batches -> compute once, store 8x.
// per-batch flat: v*81 + m*3 + c ; val = coord(v,c) + move(m,c) - 1
__global__ void vox_neigh(float* __restrict__ out) {
    unsigned t = blockIdx.x * 256 + threadIdx.x;
    if (t >= NEI_T) return;
    float4 r;
    float* rp = &r.x;
    #pragma unroll
    for (int q = 0; q < 4; q++) {
        unsigned e = t * 4u + (unsigned)q;
        unsigned v = e / 81u;
        unsigned rm = e - v * 81u;
        unsigned m = rm / 3u;
        unsigned c = rm - m * 3u;
        int val;
        if (c == 0)      val = (int)(v / 1600u) + (int)(m / 9u) - 1;
        else if (c == 1) val = (int)((v / 40u) % 40u) + (int)((m / 3u) % 3u) - 1;
        else             val = (int)(v % 40u) + (int)(m % 3u) - 1;
        rp[q] = (float)val;
    }
    #pragma unroll
    for (int b = 0; b < VB; b++)
        *(float4*)(out + O_NEI + (size_t)b * NEI_PER_B + (size_t)t * 4u) = r;
}

extern "C" void kernel_launch(void* const* d_in, const int* in_sizes, int n_in,
                              void* d_out, int out_size, void* d_ws, size_t ws_size,
                              hipStream_t stream) {
    const float* pc = (const float*)d_in[0];
    float* out = (float*)d_out;

    unsigned* seg = (unsigned*)(out + CARVE_F32_OFF);  // VB*VKEYS
    unsigned* mx  = seg + (size_t)VB * VKEYS;          // VB
    unsigned* bs  = mx + VB;                           // VB*VBLK
    unsigned* ord = bs + (size_t)VB * VBLK;            // VB*VN

    const int nclear = VB * VKEYS + VB;                // seg + mx contiguous
    vox_zero<<<(nclear + 255) / 256, 256, 0, stream>>>(seg, nclear);
    vox_hist<<<dim3(VGX, VB), 256, 0, stream>>>(pc, seg, mx);
    vox_scanA<<<dim3(VBLK, VB), 256, 0, stream>>>(seg, bs);
    vox_scanB<<<VB, 256, 0, stream>>>(bs);
    vox_scanC<<<dim3(VBLK, VB), 256, 0, stream>>>(seg, bs);
    vox_scatter<<<dim3(VGX, VB), 256, 0, stream>>>(pc, seg, ord);
    vox_emit<<<dim3(VBLK, VB), 256, 0, stream>>>(seg, mx, ord, out);
    vox_neigh<<<(NEI_T + 255) / 256, 256, 0, stream>>>(out);   // last: rewrites carve
}

// Round 11
// 287.170 us; speedup vs baseline: 1.3597x; 1.3597x over previous
//
#include <hip/hip_runtime.h>

// d_out is FLOAT32: order[8,100000] | sh[8,100000] | nei[8,40,40,40,27,3] | mask[8,40,40,40]
// R10 passed (absmax 0.0, 390us). R11: remove the 8-address atomicMax hot spot
// from vox_hist (1564 serialized RMWs/address ~= 155us) -> dedicated no-atomic
// findmax reduction kernel.

#define VB    8
#define VN    100000
#define VKEYS 64000        // 40^3 compact keys (lex == hash order)
#define VBLK  250          // VKEYS/256
#define VGX   391          // ceil(VN/256)

// f32 element offsets
#define O_ORDER 0
#define O_SH    800000
#define O_NEI   1600000
#define O_MASK  43072000
#define NEI_PER_B 5184000  // 64000*27*3 (identical values for every batch)
#define NEI_T   1296000    // NEI_PER_B/4 threads, one float4 each, 8 batch stores

// u32 scratch carved inside the nei f32 region (slots 40,000,000..41,314,008;
// nei spans [1,600,000, 43,072,000) and is fully rewritten LAST by vox_neigh).
#define CARVE_F32_OFF 40000000

__device__ __forceinline__ unsigned vox_key(const float* __restrict__ p) {
    int cx = (int)(p[0] * 39.0f);
    int cy = (int)(p[1] * 39.0f);
    int cz = (int)(p[2] * 39.0f);
    cx = cx < 0 ? 0 : (cx > 39 ? 39 : cx);
    cy = cy < 0 ? 0 : (cy > 39 ? 39 : cy);
    cz = cz < 0 ? 0 : (cz > 39 ? 39 : cz);
    return (unsigned)(cx * 1600 + cy * 40 + cz);
}

__global__ void vox_zero(unsigned* __restrict__ p, int n) {
    int i = blockIdx.x * 256 + threadIdx.x;
    if (i < n) p[i] = 0u;
}

// histogram only — no atomicMax (was 155us of 8-address serialization)
__global__ void vox_hist(const float* __restrict__ pc, unsigned* __restrict__ seg) {
    int n = blockIdx.x * 256 + threadIdx.x;
    int b = blockIdx.y;
    if (n >= VN) return;
    atomicAdd(&seg[b * VKEYS + vox_key(pc + ((size_t)b * VN + n) * 3)], 1u);
}

// max occupied bin per batch: 1 block/batch, grid-stride + LDS reduce, no atomics
__global__ void vox_findmax(const unsigned* __restrict__ seg, unsigned* __restrict__ mx) {
    int b = blockIdx.x;
    int t = threadIdx.x;
    unsigned best = 0;
    for (int bin = t; bin < VKEYS; bin += 1024)
        if (seg[b * VKEYS + bin]) best = (unsigned)bin;   // strided: later stride wins naturally? no — take max
    // (bin increases with loop, so last nonzero seen IS the max for this thread)
    __shared__ unsigned s[1024];
    s[t] = best;
    __syncthreads();
    #pragma unroll
    for (int o = 512; o; o >>= 1) {
        if (t < o) { unsigned v = s[t + o]; if (v > s[t]) s[t] = v; }
        __syncthreads();
    }
    if (t == 0) mx[b] = s[0];
}

__global__ void vox_scanA(unsigned* __restrict__ seg, unsigned* __restrict__ bs) {
    int b = blockIdx.y;
    int bin = blockIdx.x * 256 + threadIdx.x;
    __shared__ unsigned s[256];
    unsigned v = seg[b * VKEYS + bin];
    s[threadIdx.x] = v;
    __syncthreads();
    #pragma unroll
    for (int o = 1; o < 256; o <<= 1) {
        unsigned t = (threadIdx.x >= o) ? s[threadIdx.x - o] : 0u;
        __syncthreads();
        s[threadIdx.x] += t;
        __syncthreads();
    }
    seg[b * VKEYS + bin] = s[threadIdx.x] - v;   // exclusive within block
    if (threadIdx.x == 255) bs[b * VBLK + blockIdx.x] = s[255];
}

__global__ void vox_scanB(unsigned* __restrict__ bs) {
    int b = blockIdx.x;
    int t = threadIdx.x;
    __shared__ unsigned s[256];
    unsigned v = (t < VBLK) ? bs[b * VBLK + t] : 0u;
    s[t] = v;
    __syncthreads();
    #pragma unroll
    for (int o = 1; o < 256; o <<= 1) {
        unsigned tv = (t >= o) ? s[t - o] : 0u;
        __syncthreads();
        s[t] += tv;
        __syncthreads();
    }
    if (t < VBLK) bs[b * VBLK + t] = s[t] - v;
}

__global__ void vox_scanC(unsigned* __restrict__ seg, const unsigned* __restrict__ bs) {
    int b = blockIdx.y;
    int bin = blockIdx.x * 256 + threadIdx.x;
    seg[b * VKEYS + bin] += bs[b * VBLK + blockIdx.x];
}

__global__ void vox_scatter(const float* __restrict__ pc, unsigned* __restrict__ seg,
                            unsigned* __restrict__ ord) {
    int n = blockIdx.x * 256 + threadIdx.x;
    int b = blockIdx.y;
    if (n >= VN) return;
    unsigned key = vox_key(pc + ((size_t)b * VN + n) * 3);
    unsigned pos = atomicAdd(&seg[b * VKEYS + key], 1u);
    if (pos < VN) ord[(size_t)b * VN + pos] = (unsigned)n;
}

// per-bucket stable fix-up + emit order/sh/mask as f32
__global__ void vox_emit(const unsigned* __restrict__ seg, const unsigned* __restrict__ mx,
                         unsigned* __restrict__ ord, float* __restrict__ out) {
    int bin = blockIdx.x * 256 + threadIdx.x;   // == linear voxel index
    int b = blockIdx.y;
    unsigned end = seg[b * VKEYS + bin];
    unsigned st  = bin ? seg[b * VKEYS + bin - 1] : 0u;
    out[(size_t)O_MASK + (size_t)b * VKEYS + bin] =
        (end > st && (unsigned)bin != mx[b]) ? 1.0f : 0.0f;
    if (end <= st || end > VN || st > VN) return;
    unsigned* o = ord + (size_t)b * VN;
    // stable tie-break: ascending point index (jnp.argsort is stable)
    for (unsigned a = st; a + 1 < end; a++) {
        unsigned mi = a, mv = o[a];
        for (unsigned c = a + 1; c < end; c++) {
            unsigned cv = o[c];
            if (cv < mv) { mv = cv; mi = c; }
        }
        if (mi != a) { unsigned tt = o[a]; o[a] = mv; o[mi] = tt; }
    }
    int x = bin / 1600, y = (bin / 40) % 40, z = bin % 40;
    float hb = (float)(x * 10000 + y * 100 + z);
    for (unsigned q = st; q < end; q++) {
        out[(size_t)O_ORDER + (size_t)b * VN + q] = (float)o[q];
        out[(size_t)O_SH + (size_t)b * VN + q] = hb;
    }
}

// neighbour list: values identical across batches -> compute once, store 8x
__global__ void vox_neigh(float* __restrict__ out) {
    unsigned t = blockIdx.x * 256 + threadIdx.x;
    if (t >= NEI_T) return;
    float4 r;
    float* rp = &r.x;
    #pragma unroll
    for (int q = 0; q < 4; q++) {
        unsigned e = t * 4u + (unsigned)q;
        unsigned v = e / 81u;
        unsigned rm = e - v * 81u;
        unsigned m = rm / 3u;
        unsigned c = rm - m * 3u;
        int val;
        if (c == 0)      val = (int)(v / 1600u) + (int)(m / 9u) - 1;
        else if (c == 1) val = (int)((v / 40u) % 40u) + (int)((m / 3u) % 3u) - 1;
        else             val = (int)(v % 40u) + (int)(m % 3u) - 1;
        rp[q] = (float)val;
    }
    #pragma unroll
    for (int b = 0; b < VB; b++)
        *(float4*)(out + O_NEI + (size_t)b * NEI_PER_B + (size_t)t * 4u) = r;
}

extern "C" void kernel_launch(void* const* d_in, const int* in_sizes, int n_in,
                              void* d_out, int out_size, void* d_ws, size_t ws_size,
                              hipStream_t stream) {
    const float* pc = (const float*)d_in[0];
    float* out = (float*)d_out;

    unsigned* seg = (unsigned*)(out + CARVE_F32_OFF);  // VB*VKEYS
    unsigned* mx  = seg + (size_t)VB * VKEYS;          // VB
    unsigned* bs  = mx + VB;                           // VB*VBLK
    unsigned* ord = bs + (size_t)VB * VBLK;            // VB*VN

    const int nclear = VB * VKEYS;
    vox_zero<<<(nclear + 255) / 256, 256, 0, stream>>>(seg, nclear);
    vox_hist<<<dim3(VGX, VB), 256, 0, stream>>>(pc, seg);
    vox_findmax<<<VB, 1024, 0, stream>>>(seg, mx);
    vox_scanA<<<dim3(VBLK, VB), 256, 0, stream>>>(seg, bs);
    vox_scanB<<<VB, 256, 0, stream>>>(bs);
    vox_scanC<<<dim3(VBLK, VB), 256, 0, stream>>>(seg, bs);
    vox_scatter<<<dim3(VGX, VB), 256, 0, stream>>>(pc, seg, ord);
    vox_emit<<<dim3(VBLK, VB), 256, 0, stream>>>(seg, mx, ord, out);
    vox_neigh<<<(NEI_T + 255) / 256, 256, 0, stream>>>(out);   // last: rewrites carve
}

// Round 13
// 266.450 us; speedup vs baseline: 1.4654x; 1.0778x over previous
//
#include <hip/hip_runtime.h>

// d_out is FLOAT32: order[8,100000] | sh[8,100000] | nei[8,40,40,40,27,3] | mask[8,40,40,40]
// R11: 287us. R12: fold scanC into scatter/emit, fold findmax into scanA/scanB
// (7 launches, two fewer full passes over seg). Poison-fill floor theory under test.

#define VB    8
#define VN    100000
#define VKEYS 64000        // 40^3 compact keys (lex == hash order)
#define VBLK  250          // VKEYS/256
#define VGX   391          // ceil(VN/256)

// f32 element offsets
#define O_ORDER 0
#define O_SH    800000
#define O_NEI   1600000
#define O_MASK  43072000
#define NEI_PER_B 5184000  // 64000*27*3 (identical values for every batch)
#define NEI_T   1296000    // NEI_PER_B/4 threads, one float4 each, 8 batch stores

// u32 scratch carved inside the nei f32 region (slots 40,000,000..41,316,008;
// nei spans [1,600,000, 43,072,000) and is fully rewritten LAST by vox_neigh).
#define CARVE_F32_OFF 40000000

__device__ __forceinline__ unsigned vox_key(const float* __restrict__ p) {
    int cx = (int)(p[0] * 39.0f);
    int cy = (int)(p[1] * 39.0f);
    int cz = (int)(p[2] * 39.0f);
    cx = cx < 0 ? 0 : (cx > 39 ? 39 : cx);
    cy = cy < 0 ? 0 : (cy > 39 ? 39 : cy);
    cz = cz < 0 ? 0 : (cz > 39 ? 39 : cz);
    return (unsigned)(cx * 1600 + cy * 40 + cz);
}

__global__ void vox_zero(unsigned* __restrict__ p, int n) {
    int i = blockIdx.x * 256 + threadIdx.x;
    if (i < n) p[i] = 0u;
}

// histogram (scattered atomics only)
__global__ void vox_hist(const float* __restrict__ pc, unsigned* __restrict__ seg) {
    int n = blockIdx.x * 256 + threadIdx.x;
    int b = blockIdx.y;
    if (n >= VN) return;
    atomicAdd(&seg[b * VKEYS + vox_key(pc + ((size_t)b * VN + n) * 3)], 1u);
}

// per-256-bin exclusive scan in place + block sums + per-block max occupied bin
__global__ void vox_scanA(unsigned* __restrict__ seg, unsigned* __restrict__ bs,
                          unsigned* __restrict__ bmax) {
    int b = blockIdx.y;
    int bin = blockIdx.x * 256 + threadIdx.x;
    __shared__ unsigned s[256];
    __shared__ unsigned m[256];
    unsigned v = seg[b * VKEYS + bin];
    s[threadIdx.x] = v;
    m[threadIdx.x] = v ? (unsigned)bin : 0u;
    __syncthreads();
    #pragma unroll
    for (int o = 1; o < 256; o <<= 1) {
        unsigned t = (threadIdx.x >= o) ? s[threadIdx.x - o] : 0u;
        __syncthreads();
        s[threadIdx.x] += t;
        __syncthreads();
    }
    seg[b * VKEYS + bin] = s[threadIdx.x] - v;   // block-local exclusive
    if (threadIdx.x == 255) bs[b * VBLK + blockIdx.x] = s[255];
    // max-occupied-bin reduce (m untouched during the scan)
    #pragma unroll
    for (int o = 128; o; o >>= 1) {
        if (threadIdx.x < o) { unsigned u = m[threadIdx.x + o]; if (u > m[threadIdx.x]) m[threadIdx.x] = u; }
        __syncthreads();
    }
    if (threadIdx.x == 0) bmax[b * VBLK + blockIdx.x] = m[0];
}

// exclusive scan of 250 block sums per batch + batch max occupied bin
__global__ void vox_scanB(unsigned* __restrict__ bs, const unsigned* __restrict__ bmax,
                          unsigned* __restrict__ mx) {
    int b = blockIdx.x;
    int t = threadIdx.x;
    __shared__ unsigned s[256];
    unsigned v = (t < VBLK) ? bs[b * VBLK + t] : 0u;
    s[t] = v;
    __syncthreads();
    #pragma unroll
    for (int o = 1; o < 256; o <<= 1) {
        unsigned tv = (t >= o) ? s[t - o] : 0u;
        __syncthreads();
        s[t] += tv;
        __syncthreads();
    }
    if (t < VBLK) bs[b * VBLK + t] = s[t] - v;
    __syncthreads();
    unsigned mm = (t < VBLK) ? bmax[b * VBLK + t] : 0u;
    s[t] = mm;
    __syncthreads();
    #pragma unroll
    for (int o = 128; o; o >>= 1) {
        if (t < o) { unsigned u = s[t + o]; if (u > s[t]) s[t] = u; }
        __syncthreads();
    }
    if (t == 0) mx[b] = s[0];
}

// scatter with on-the-fly global offset (seg block-local + bs block base)
__global__ void vox_scatter(const float* __restrict__ pc, unsigned* __restrict__ seg,
                            const unsigned* __restrict__ bs, unsigned* __restrict__ ord) {
    int n = blockIdx.x * 256 + threadIdx.x;
    int b = blockIdx.y;
    if (n >= VN) return;
    unsigned key = vox_key(pc + ((size_t)b * VN + n) * 3);
    unsigned pos = atomicAdd(&seg[b * VKEYS + key], 1u) + bs[b * VBLK + (key >> 8)];
    if (pos < VN) ord[(size_t)b * VN + pos] = (unsigned)n;
}

// per-bucket stable fix-up + emit order/sh/mask as f32
// post-scatter: seg[bin]+bs[bin>>8] = global end; seg[bin-1]+bs[(bin-1)>>8] = start
__global__ void vox_emit(const unsigned* __restrict__ seg, const unsigned* __restrict__ bs,
                         const unsigned* __restrict__ mx, unsigned* __restrict__ ord,
                         float* __restrict__ out) {
    int bin = blockIdx.x * 256 + threadIdx.x;   // == linear voxel index
    int b = blockIdx.y;
    unsigned end = seg[b * VKEYS + bin] + bs[b * VBLK + (bin >> 8)];
    unsigned st = 0;
    if (bin) st = seg[b * VKEYS + bin - 1] + bs[b * VBLK + ((bin - 1) >> 8)];
    out[(size_t)O_MASK + (size_t)b * VKEYS + bin] =
        (end > st && (unsigned)bin != mx[b]) ? 1.0f : 0.0f;
    if (end <= st || end > VN || st > VN) return;
    unsigned* o = ord + (size_t)b * VN;
    // stable tie-break: ascending point index (jnp.argsort is stable)
    for (unsigned a = st; a + 1 < end; a++) {
        unsigned mi = a, mv = o[a];
        for (unsigned c = a + 1; c < end; c++) {
            unsigned cv = o[c];
            if (cv < mv) { mv = cv; mi = c; }
        }
        if (mi != a) { unsigned tt = o[a]; o[a] = mv; o[mi] = tt; }
    }
    int x = bin / 1600, y = (bin / 40) % 40, z = bin % 40;
    float hb = (float)(x * 10000 + y * 100 + z);
    for (unsigned q = st; q < end; q++) {
        out[(size_t)O_ORDER + (size_t)b * VN + q] = (float)o[q];
        out[(size_t)O_SH + (size_t)b * VN + q] = hb;
    }
}

// neighbour list: values identical across batches -> compute once, store 8x
__global__ void vox_neigh(float* __restrict__ out) {
    unsigned t = blockIdx.x * 256 + threadIdx.x;
    if (t >= NEI_T) return;
    float4 r;
    float* rp = &r.x;
    #pragma unroll
    for (int q = 0; q < 4; q++) {
        unsigned e = t * 4u + (unsigned)q;
        unsigned v = e / 81u;
        unsigned rm = e - v * 81u;
        unsigned m = rm / 3u;
        unsigned c = rm - m * 3u;
        int val;
        if (c == 0)      val = (int)(v / 1600u) + (int)(m / 9u) - 1;
        else if (c == 1) val = (int)((v / 40u) % 40u) + (int)((m / 3u) % 3u) - 1;
        else             val = (int)(v % 40u) + (int)(m % 3u) - 1;
        rp[q] = (float)val;
    }
    #pragma unroll
    for (int b = 0; b < VB; b++)
        *(float4*)(out + O_NEI + (size_t)b * NEI_PER_B + (size_t)t * 4u) = r;
}

extern "C" void kernel_launch(void* const* d_in, const int* in_sizes, int n_in,
                              void* d_out, int out_size, void* d_ws, size_t ws_size,
                              hipStream_t stream) {
    const float* pc = (const float*)d_in[0];
    float* out = (float*)d_out;

    unsigned* seg  = (unsigned*)(out + CARVE_F32_OFF);  // VB*VKEYS
    unsigned* mx   = seg + (size_t)VB * VKEYS;          // VB
    unsigned* bs   = mx + VB;                           // VB*VBLK
    unsigned* bmax = bs + (size_t)VB * VBLK;            // VB*VBLK
    unsigned* ord  = bmax + (size_t)VB * VBLK;          // VB*VN

    const int nclear = VB * VKEYS;
    vox_zero<<<(nclear + 255) / 256, 256, 0, stream>>>(seg, nclear);
    vox_hist<<<dim3(VGX, VB), 256, 0, stream>>>(pc, seg);
    vox_scanA<<<dim3(VBLK, VB), 256, 0, stream>>>(seg, bs, bmax);
    vox_scanB<<<VB, 256, 0, stream>>>(bs, bmax, mx);
    vox_scatter<<<dim3(VGX, VB), 256, 0, stream>>>(pc, seg, bs, ord);
    vox_emit<<<dim3(VBLK, VB), 256, 0, stream>>>(seg, bs, mx, ord, out);
    vox_neigh<<<(NEI_T + 255) / 256, 256, 0, stream>>>(out);   // last: rewrites carve
}